// Round 4
// baseline (411.316 us; speedup 1.0000x reference)
//
#include <hip/hip_runtime.h>

#define Bb 2
#define Tt 2048
#define Dd 1024
#define Hh 16
#define LDC 4480

typedef __attribute__((ext_vector_type(8))) short s16x8;
typedef __attribute__((ext_vector_type(4))) float f32x4;

__device__ __forceinline__ float bf2f(unsigned short u) {
  unsigned v = ((unsigned)u) << 16;
  union { unsigned u; float f; } c; c.u = v; return c.f;
}
__device__ __forceinline__ unsigned short f2bf(float f) {
  union { float f; unsigned u; } c; c.f = f;
  unsigned u = c.u + 0x7fffu + ((c.u >> 16) & 1u);
  return (unsigned short)(u >> 16);
}
__device__ __forceinline__ float sigm(float x) { return 1.f / (1.f + expf(-x)); }

__device__ __forceinline__ void async_copy16(void* lds, const void* g) {
  __builtin_amdgcn_global_load_lds(
      (const __attribute__((address_space(1))) unsigned int*)g,
      (__attribute__((address_space(3))) unsigned int*)lds, 16, 0, 0);
}

// ---------------- cast x to bf16 ----------------

__global__ __launch_bounds__(256) void cast_x_kernel(const float* __restrict__ x,
                                                     unsigned short* __restrict__ xb) {
  int i = blockIdx.x * 256 + threadIdx.x;
  const float4* xv = reinterpret_cast<const float4*>(x);
  float4 v = xv[i];
  unsigned long long pk = (unsigned long long)f2bf(v.x)
                        | ((unsigned long long)f2bf(v.y) << 16)
                        | ((unsigned long long)f2bf(v.z) << 32)
                        | ((unsigned long long)f2bf(v.w) << 48);
  reinterpret_cast<unsigned long long*>(xb)[i] = pk;
}

// ---------------- fused weight concat + transpose + cast ----------------
// WT[n][k] = concat-weight[k][n] for the (1024 x 4480) fused projection.
// Segments: [0,3072) qkv | [3072..3328) 4x64 line proj | [3328,3344) memg |
//           [3344,3392) zero | [3392,4416) memv | [4416,4480) zero.

__global__ __launch_bounds__(256) void build_wt_kernel(const float* __restrict__ qkv_w,
                                                       const float* __restrict__ w1w,
                                                       const float* __restrict__ w2w,
                                                       const float* __restrict__ w1r,
                                                       const float* __restrict__ w2r,
                                                       const float* __restrict__ memg_w,
                                                       const float* __restrict__ memv_w,
                                                       unsigned short* __restrict__ WT) {
  __shared__ float tile[32][33];
  int n0 = blockIdx.x * 32, k0 = blockIdx.y * 32;
  int tx = threadIdx.x & 31, ty = threadIdx.x >> 5;
#pragma unroll
  for (int i = 0; i < 4; i++) {
    int k = k0 + ty + i * 8, n = n0 + tx;
    float v;
    if (n < 3072)       v = qkv_w[(size_t)k * 3072 + n];
    else if (n < 3136)  v = w1w[k * 64 + (n - 3072)];
    else if (n < 3200)  v = w2w[k * 64 + (n - 3136)];
    else if (n < 3264)  v = w1r[k * 64 + (n - 3200)];
    else if (n < 3328)  v = w2r[k * 64 + (n - 3264)];
    else if (n < 3344)  v = memg_w[k * 16 + (n - 3328)];
    else if (n < 3392)  v = 0.f;
    else if (n < 4416)  v = memv_w[(size_t)k * 1024 + (n - 3392)];
    else                v = 0.f;
    tile[ty + i * 8][tx] = v;
  }
  __syncthreads();
#pragma unroll
  for (int i = 0; i < 4; i++) {
    int n = n0 + ty + i * 8, k = k0 + tx;
    WT[(size_t)n * 1024 + k] = f2bf(tile[tx][ty + i * 8]);
  }
}

// src: (1024, ncols) fp32 row-major -> dst: (ncols, 1024) bf16 row-major
__global__ __launch_bounds__(256) void transpose_cast_kernel(const float* __restrict__ src,
                                                             int ncols,
                                                             unsigned short* __restrict__ dst) {
  __shared__ float tile[32][33];
  int n0 = blockIdx.x * 32, k0 = blockIdx.y * 32;
  int tx = threadIdx.x & 31, ty = threadIdx.x >> 5;
#pragma unroll
  for (int i = 0; i < 4; i++) {
    int k = k0 + ty + i * 8, n = n0 + tx;
    tile[ty + i * 8][tx] = (n < ncols) ? src[(size_t)k * ncols + n] : 0.f;
  }
  __syncthreads();
#pragma unroll
  for (int i = 0; i < 4; i++) {
    int n = n0 + ty + i * 8, k = k0 + tx;
    if (n < ncols) dst[(size_t)n * 1024 + k] = f2bf(tile[tx][ty + i * 8]);
  }
}

__global__ void bias_fill_kernel(const float* __restrict__ qkv_b,
                                 const float* __restrict__ memg_b,
                                 const float* __restrict__ memv_b,
                                 float* __restrict__ bias) {
  int i = blockIdx.x * 256 + threadIdx.x;
  if (i >= LDC) return;
  float v = 0.f;
  if (i < 3072) v = qkv_b[i];
  else if (i >= 3328 && i < 3344) v = memg_b[i - 3328];
  else if (i >= 3392 && i < 4416) v = memv_b[i - 3392];
  bias[i] = v;
}

// ---------------- bf16 MFMA GEMM: C(M,N) = A(M,K) * B^T(N,K) + bias ----------------

template <bool OUT_BF16>
__global__ __launch_bounds__(256) void gemm_kernel(const unsigned short* __restrict__ A,
                                                   const unsigned short* __restrict__ Bt,
                                                   void* __restrict__ Cout,
                                                   const float* __restrict__ bias,
                                                   int M, int N, int K) {
  __shared__ unsigned short As[128 * 32];
  __shared__ unsigned short Bs[128 * 32];
  const int tid = threadIdx.x;
  const int lane = tid & 63, wid = tid >> 6;
  const int quad = lane >> 4, c16 = lane & 15;
  const int mBase = blockIdx.y * 128, nBase = blockIdx.x * 128;
  const int wm = wid >> 1, wn = wid & 1;
  const int srow = lane >> 2, scol = (lane & 3) << 3;

  f32x4 acc[4][4] = {};
  for (int k0 = 0; k0 < K; k0 += 32) {
    __syncthreads();
#pragma unroll
    for (int j = 0; j < 2; j++) {
      int rr = wid * 32 + j * 16;
      async_copy16(&As[rr * 32], &A[(size_t)(mBase + rr + srow) * K + k0 + scol]);
      async_copy16(&Bs[rr * 32], &Bt[(size_t)(nBase + rr + srow) * K + k0 + scol]);
    }
    __syncthreads();
    s16x8 af[4], bf[4];
#pragma unroll
    for (int mt = 0; mt < 4; mt++)
      af[mt] = *(const s16x8*)&As[(wm * 64 + mt * 16 + c16) * 32 + quad * 8];
#pragma unroll
    for (int nt = 0; nt < 4; nt++)
      bf[nt] = *(const s16x8*)&Bs[(wn * 64 + nt * 16 + c16) * 32 + quad * 8];
#pragma unroll
    for (int mt = 0; mt < 4; mt++)
#pragma unroll
      for (int nt = 0; nt < 4; nt++)
        acc[mt][nt] = __builtin_amdgcn_mfma_f32_16x16x32_bf16(af[mt], bf[nt], acc[mt][nt], 0, 0, 0);
  }
#pragma unroll
  for (int mt = 0; mt < 4; mt++)
#pragma unroll
    for (int nt = 0; nt < 4; nt++) {
      int col = nBase + wn * 64 + nt * 16 + c16;
      float bv = bias[col];
#pragma unroll
      for (int r = 0; r < 4; r++) {
        int row = mBase + wm * 64 + mt * 16 + quad * 4 + r;
        float v = acc[mt][nt][r] + bv;
        if (OUT_BF16)
          ((unsigned short*)Cout)[(size_t)row * N + col] = f2bf(v);
        else
          ((float*)Cout)[(size_t)row * N + col] = v;
      }
    }
}

// ---------------- repack K compact + V transposed ----------------

__global__ __launch_bounds__(256) void repack_kernel(const unsigned short* __restrict__ Cq,
                                                     unsigned short* __restrict__ Kc,
                                                     unsigned short* __restrict__ Vt) {
  int tb = blockIdx.x & 31, h = (blockIdx.x >> 5) & 15, b = blockIdx.x >> 9;
  int tid = threadIdx.x;
  __shared__ unsigned short vtile[64][68];
  int row = tid >> 2, col0 = (tid & 3) * 16;
  int t = tb * 64 + row;
  size_t src = (size_t)(b * Tt + t) * LDC + h * 64 + col0;
  s16x8 k0 = *(const s16x8*)&Cq[src + 1024];
  s16x8 k1 = *(const s16x8*)&Cq[src + 1024 + 8];
  size_t kdst = ((size_t)(b * Hh + h) * Tt + t) * 64 + col0;
  *(s16x8*)&Kc[kdst] = k0;
  *(s16x8*)&Kc[kdst + 8] = k1;
  s16x8 v0 = *(const s16x8*)&Cq[src + 2048];
  s16x8 v1 = *(const s16x8*)&Cq[src + 2048 + 8];
#pragma unroll
  for (int e = 0; e < 8; e++) {
    vtile[row][col0 + e] = (unsigned short)v0[e];
    vtile[row][col0 + 8 + e] = (unsigned short)v1[e];
  }
  __syncthreads();
  int tloc = tid & 63, dbase = (tid >> 6) * 16;
  size_t vb = ((size_t)(b * Hh + h) * 64) * Tt + tb * 64 + tloc;
#pragma unroll
  for (int dd = 0; dd < 16; dd++) {
    int d = dbase + dd;
    Vt[vb + (size_t)d * Tt] = vtile[tloc][d];
  }
}

// ---------------- key-split MFMA flash attention (causal, fixed-max softmax) ----
// Fixed max=0 makes chunk partials additive: o_part = sum p*v, l_part = sum p.
// Wave = (qtile, key-chunk of 1024). Chunks per qtile: 1 for qt<64, 2 for qt>=64.
// 6144 waves total (24/CU). Partials: po bf16 [(c*2+b), t, 1024], pll fp32.

__global__ __launch_bounds__(128) void attn_kernel(const unsigned short* __restrict__ Cq,
                                                   const unsigned short* __restrict__ Kc,
                                                   const unsigned short* __restrict__ Vt,
                                                   unsigned short* __restrict__ po,
                                                   float* __restrict__ pll) {
  const int w = threadIdx.x >> 6, lane = threadIdx.x & 63;
  const int f = blockIdx.x * 2 + w;           // 0..191
  const int bh = blockIdx.y, b = bh >> 4, h = bh & 15;
  const int quad = lane >> 4, c16 = lane & 15;
  int qt, c;
  if (f < 64) { qt = f; c = 0; }
  else { int j = f - 64; qt = 64 + (j >> 1); c = j & 1; }
  const int q0 = qt * 16;
  const int kstart = c << 10;
  const int kend = min(kstart + 1024, q0 + 16);
  __shared__ unsigned short pls[2][16 * 40];
  unsigned short* pl = pls[w];

  size_t rowQ = (size_t)(b * Tt + q0 + c16) * LDC + h * 64;
  s16x8 qf0 = *(const s16x8*)&Cq[rowQ + quad * 8];
  s16x8 qf1 = *(const s16x8*)&Cq[rowQ + 32 + quad * 8];

  const unsigned short* Kb = Kc + (size_t)bh * Tt * 64;
  const unsigned short* Vb = Vt + (size_t)bh * 64 * Tt;

  float l_i[4] = {0.f, 0.f, 0.f, 0.f};
  f32x4 o[4] = {};

  s16x8 kf[2][2], vf[4];
#pragma unroll
  for (int g = 0; g < 2; g++) {
    const unsigned short* kr = Kb + (size_t)(kstart + g * 16 + c16) * 64 + quad * 8;
    kf[g][0] = *(const s16x8*)kr;
    kf[g][1] = *(const s16x8*)(kr + 32);
  }
#pragma unroll
  for (int nt = 0; nt < 4; nt++)
    vf[nt] = *(const s16x8*)(Vb + (size_t)(nt * 16 + c16) * Tt + kstart + quad * 8);

  for (int ks = kstart; ks < kend; ks += 32) {
    s16x8 kf2[2][2], vf2[4];
    bool more = (ks + 32 < kend);
    if (more) {
#pragma unroll
      for (int g = 0; g < 2; g++) {
        const unsigned short* kr = Kb + (size_t)(ks + 32 + g * 16 + c16) * 64 + quad * 8;
        kf2[g][0] = *(const s16x8*)kr;
        kf2[g][1] = *(const s16x8*)(kr + 32);
      }
#pragma unroll
      for (int nt = 0; nt < 4; nt++)
        vf2[nt] = *(const s16x8*)(Vb + (size_t)(nt * 16 + c16) * Tt + ks + 32 + quad * 8);
    }

    f32x4 s0 = {}, s1 = {};
    s0 = __builtin_amdgcn_mfma_f32_16x16x32_bf16(qf0, kf[0][0], s0, 0, 0, 0);
    s0 = __builtin_amdgcn_mfma_f32_16x16x32_bf16(qf1, kf[0][1], s0, 0, 0, 0);
    s1 = __builtin_amdgcn_mfma_f32_16x16x32_bf16(qf0, kf[1][0], s1, 0, 0, 0);
    s1 = __builtin_amdgcn_mfma_f32_16x16x32_bf16(qf1, kf[1][1], s1, 0, 0, 0);
    bool need_mask = (ks + 31 > q0);
#pragma unroll
    for (int r = 0; r < 4; r++) {
      float v0 = s0[r] * 0.125f;
      float v1 = s1[r] * 0.125f;
      if (need_mask) {
        int qr = q0 + quad * 4 + r;
        v0 = (ks + c16      <= qr) ? v0 : -1e30f;
        v1 = (ks + 16 + c16 <= qr) ? v1 : -1e30f;
      }
      float p0 = __expf(v0);
      float p1 = __expf(v1);
      l_i[r] += p0 + p1;
      pl[(quad * 4 + r) * 40 + c16]      = f2bf(p0);
      pl[(quad * 4 + r) * 40 + 16 + c16] = f2bf(p1);
    }
    asm volatile("s_waitcnt lgkmcnt(0)" ::: "memory");
    s16x8 pa = *(const s16x8*)&pl[c16 * 40 + quad * 8];
#pragma unroll
    for (int nt = 0; nt < 4; nt++)
      o[nt] = __builtin_amdgcn_mfma_f32_16x16x32_bf16(pa, vf[nt], o[nt], 0, 0, 0);

    if (more) {
#pragma unroll
      for (int g = 0; g < 2; g++) { kf[g][0] = kf2[g][0]; kf[g][1] = kf2[g][1]; }
#pragma unroll
      for (int nt = 0; nt < 4; nt++) vf[nt] = vf2[nt];
    }
  }

#pragma unroll
  for (int r = 0; r < 4; r++) {
    float l = l_i[r];
    l += __shfl_xor(l, 1, 64); l += __shfl_xor(l, 2, 64);
    l += __shfl_xor(l, 4, 64); l += __shfl_xor(l, 8, 64);
    l_i[r] = l;
  }
  if (c16 == 0) {
#pragma unroll
    for (int r = 0; r < 4; r++)
      pll[(size_t)(c * 32 + bh) * Tt + q0 + quad * 4 + r] = l_i[r];
  }
#pragma unroll
  for (int r = 0; r < 4; r++) {
    int row = q0 + quad * 4 + r;
    size_t base = ((size_t)(c * 2 + b) * Tt + row) * Dd + h * 64;
#pragma unroll
    for (int nt = 0; nt < 4; nt++)
      po[base + nt * 16 + c16] = f2bf(o[nt][r]);
  }
}

// ---------------- Plucker lines ----------------

__device__ __forceinline__ void ext6(const float* p, const float* q, float* L) {
  L[0] = p[0] * q[1] - p[1] * q[0];
  L[1] = p[0] * q[2] - p[2] * q[0];
  L[2] = p[0] * q[3] - p[3] * q[0];
  L[3] = p[1] * q[2] - p[2] * q[1];
  L[4] = p[1] * q[3] - p[3] * q[1];
  L[5] = p[2] * q[3] - p[3] * q[2];
  float n = sqrtf(L[0]*L[0] + L[1]*L[1] + L[2]*L[2] + L[3]*L[3] + L[4]*L[4] + L[5]*L[5]);
  float inv = 1.f / fmaxf(n, 1e-12f);
#pragma unroll
  for (int k = 0; k < 6; k++) L[k] *= inv;
}

__global__ void lines_kernel(const unsigned short* __restrict__ Cq,
                             float* __restrict__ Jw, float* __restrict__ Jr,
                             float* __restrict__ rd) {
  int idx = blockIdx.x * 256 + threadIdx.x;
  int h = idx & 15, t = (idx >> 4) & 2047, b = idx >> 15;
  size_t row = (size_t)(b * Tt + t) * LDC;
  float w1[4], w2[4], r1[4], r2[4];
#pragma unroll
  for (int k = 0; k < 4; k++) {
    w1[k] = (t > 0) ? bf2f(Cq[row - LDC + 3072 + h * 4 + k]) : 0.f;
    w2[k] = bf2f(Cq[row + 3136 + h * 4 + k]);
    r1[k] = bf2f(Cq[row + 3200 + h * 4 + k]);
    r2[k] = bf2f(Cq[row + 3264 + h * 4 + k]);
  }
  float Lw[6], Lr[6];
  ext6(w1, w2, Lw);
  ext6(r1, r2, Lr);
  size_t ob = ((size_t)(b * Hh + h) * Tt + t) * 6;
  Jw[ob + 0] = Lw[5]; Jw[ob + 1] = -Lw[4]; Jw[ob + 2] = Lw[3];
  Jw[ob + 3] = Lw[2]; Jw[ob + 4] = -Lw[1]; Jw[ob + 5] = Lw[0];
  Jr[ob + 0] = Lr[5]; Jr[ob + 1] = -Lr[4]; Jr[ob + 2] = Lr[3];
  Jr[ob + 3] = Lr[2]; Jr[ob + 4] = -Lr[1]; Jr[ob + 5] = Lr[0];
#pragma unroll
  for (int k = 0; k < 6; k++) rd[ob + k] = Lr[k];
}

// ---------------- chunked decay scan ----------------

__global__ __launch_bounds__(64) void scanA_kernel(const float* __restrict__ Jw,
                                                   const float* __restrict__ Jr,
                                                   const float* __restrict__ decay_logits,
                                                   float* __restrict__ chunkA) {
  int blk = blockIdx.x;
  int chunk = blk & 15, bh = (blk >> 4) & 31, type = blk >> 9;
  int lane = threadIdx.x;
  const float* V = (type == 0 ? Jw : Jr) + ((size_t)bh * Tt + chunk * 128) * 6;
  __shared__ float v[768];
  for (int i = lane; i < 768; i += 64) v[i] = V[i];
  __syncthreads();
  float d = sigm(decay_logits[bh & 15]);
  int ll = lane < 36 ? lane : 35;
  int i6 = ll / 6, j6 = ll % 6;
  float A = 0.f;
  for (int s = 0; s < 128; s++) A = d * A + v[s * 6 + i6] * v[s * 6 + j6];
  if (lane < 36) chunkA[((size_t)(type * 32 + bh) * 16 + chunk) * 36 + lane] = A;
}

__global__ void scanA2_kernel(const float* __restrict__ chunkA,
                              const float* __restrict__ decay_logits,
                              float* __restrict__ Bst) {
  int idx = blockIdx.x * 256 + threadIdx.x;
  if (idx >= 2 * 32 * 36) return;
  int entry = idx % 36, bh = (idx / 36) % 32, type = idx / (36 * 32);
  float d = sigm(decay_logits[bh & 15]);
  float dS = powf(d, 128.f);
  float Bv = 0.f;
  size_t base = (size_t)(type * 32 + bh) * 16;
  for (int c = 0; c < 16; c++) {
    Bst[(base + c) * 36 + entry] = Bv;
    Bv = dS * Bv + d * chunkA[(base + c) * 36 + entry];
  }
}

// Quadratic-form rewrite: score(t) = d^tl * (u^T B u) + sum_{s<tl} d^(tl-s) (u.w_s)^2
// One thread per t. Broadcast LDS reads, ~8cyc/step chain (vs 6 shuffles before).

__global__ __launch_bounds__(128) void scanB_kernel(const float* __restrict__ Jw,
                                                    const float* __restrict__ Jr,
                                                    const float* __restrict__ rd,
                                                    const float* __restrict__ Bst,
                                                    const float* __restrict__ decay_logits,
                                                    float* __restrict__ score_w,
                                                    float* __restrict__ score_r) {
  int blk = blockIdx.x;
  int chunk = blk & 15, bh = (blk >> 4) & 31, type = blk >> 9;
  int tl = threadIdx.x;
  size_t tb = ((size_t)bh * Tt + chunk * 128) * 6;
  const float* U = (type == 0 ? rd : Jw) + tb;
  const float* W = (type == 0 ? Jw : Jr) + tb;
  __shared__ float wv[768];
  __shared__ float Bm[36];
  for (int i = tl; i < 768; i += 128) wv[i] = W[i];
  if (tl < 36) Bm[tl] = Bst[((size_t)(type * 32 + bh) * 16 + chunk) * 36 + tl];
  __syncthreads();
  float d = sigm(decay_logits[bh & 15]);
  float u[6];
#pragma unroll
  for (int i = 0; i < 6; i++) u[i] = U[tl * 6 + i];
  float q = 0.f;
#pragma unroll
  for (int i = 0; i < 6; i++) {
    float bi = 0.f;
#pragma unroll
    for (int j = 0; j < 6; j++) bi += Bm[i * 6 + j] * u[j];
    q += u[i] * bi;
  }
  float acc = 0.f;
  for (int s = 0; s < tl; s++) {
    const float* ws = &wv[s * 6];
    float dot = u[0]*ws[0] + u[1]*ws[1] + u[2]*ws[2] + u[3]*ws[3] + u[4]*ws[4] + u[5]*ws[5];
    acc = d * (acc + dot * dot);
  }
  float score = acc + powf(d, (float)tl) * q;
  float* outp = (type == 0 ? score_w : score_r);
  outp[(size_t)bh * Tt + chunk * 128 + tl] = score;
}

// ---------------- gate + combine (+ key-split partial reduction) ----------------

__global__ __launch_bounds__(256) void combine_kernel(const unsigned short* __restrict__ po,
                                                      const float* __restrict__ pll,
                                                      const unsigned short* __restrict__ Cq,
                                                      const float* __restrict__ score_w,
                                                      const float* __restrict__ score_r,
                                                      const float* __restrict__ mem_scale,
                                                      const float* __restrict__ rw_mix,
                                                      unsigned short* __restrict__ fused) {
  __shared__ float tmp[16], invl[16];
  int rowi = blockIdx.x;
  int b = rowi >> 11, t = rowi & 2047;
  bool two = (t >= 1024);
  float alpha = sigm(rw_mix[0]);
  if (threadIdx.x < 16) {
    int h = threadIdx.x;
    int bh = b * 16 + h;
    float l = pll[(size_t)bh * Tt + t];
    if (two) l += pll[(size_t)(32 + bh) * Tt + t];
    invl[h] = 1.f / l;
    size_t sh = (size_t)bh * Tt + t;
    float ms = (1.f - alpha) * score_w[sh] + alpha * score_r[sh];
    float gate = sigm(bf2f(Cq[(size_t)rowi * LDC + 3328 + h]));
    tmp[h] = sigm(ms * mem_scale[h]) * gate;
  }
  __syncthreads();
  float g = 0.f;
#pragma unroll
  for (int h = 0; h < 16; h++) g += tmp[h];
  g *= (1.f / 16.f);
  for (int d = threadIdx.x; d < Dd; d += 256) {
    float ov = bf2f(po[((size_t)b * Tt + t) * Dd + d]);
    if (two) ov += bf2f(po[((size_t)(2 + b) * Tt + t) * Dd + d]);
    float sv = ov * invl[d >> 6];
    float mv = bf2f(Cq[(size_t)rowi * LDC + 3392 + d]);
    fused[(size_t)rowi * Dd + d] = f2bf(sv + g * mv);
  }
}

// ---------------- launch ----------------

extern "C" void kernel_launch(void* const* d_in, const int* in_sizes, int n_in,
                              void* d_out, int out_size, void* d_ws, size_t ws_size,
                              hipStream_t stream) {
  (void)in_sizes; (void)n_in; (void)out_size; (void)ws_size;
  const float* x         = (const float*)d_in[0];
  const float* qkv_w     = (const float*)d_in[1];
  const float* qkv_b     = (const float*)d_in[2];
  const float* w1w       = (const float*)d_in[3];
  const float* w2w       = (const float*)d_in[4];
  const float* w1r       = (const float*)d_in[5];
  const float* w2r       = (const float*)d_in[6];
  const float* memv_w    = (const float*)d_in[7];
  const float* memv_b    = (const float*)d_in[8];
  const float* memg_w    = (const float*)d_in[9];
  const float* memg_b    = (const float*)d_in[10];
  const float* mem_scale = (const float*)d_in[11];
  const float* rw_mix    = (const float*)d_in[12];
  const float* out_w     = (const float*)d_in[13];
  const float* out_b     = (const float*)d_in[14];
  const float* decay_l   = (const float*)d_in[15];

  char* w = (char*)d_ws;
  unsigned short* xb    = (unsigned short*)(w + 0);          //  8388608
  unsigned short* Kc    = (unsigned short*)(w + 0);          //  overlay (xb dead after gemm)
  unsigned short* WT    = (unsigned short*)(w + 8388608);    //  9175040
  unsigned short* Vt    = (unsigned short*)(w + 8388608);    //  overlay (WT dead after gemm)
  unsigned short* outT  = (unsigned short*)(w + 17563648);   //  2097152
  float*          biasC = (float*)(w + 19660800);            //    17920
  unsigned short* Cbuf  = (unsigned short*)(w + 19678720);   // 36700160
  unsigned short* po    = (unsigned short*)(w + 56378880);   // 16777216  (4,2048,1024) bf16
  float*          pll   = (float*)(w + 73156096);            //   524288  (2,32,2048) fp32
  float*          Jw    = (float*)(w + 73680384);            //  1572864
  float*          Jr    = (float*)(w + 75253248);            //  1572864
  float*          rd    = (float*)(w + 76826112);            //  1572864
  float*          chA   = (float*)(w + 78398976);            //   147456
  float*          Bst   = (float*)(w + 78546432);            //   147456
  float*          sw    = (float*)(w + 78693888);            //   262144
  float*          sr    = (float*)(w + 78956032);            //   262144
  unsigned short* fused = (unsigned short*)(w + 79218176);   //  8388608

  cast_x_kernel<<<4096, 256, 0, stream>>>(x, xb);
  build_wt_kernel<<<dim3(140, 32), 256, 0, stream>>>(qkv_w, w1w, w2w, w1r, w2r,
                                                     memg_w, memv_w, WT);
  transpose_cast_kernel<<<dim3(32, 32), 256, 0, stream>>>(out_w, 1024, outT);
  bias_fill_kernel<<<18, 256, 0, stream>>>(qkv_b, memg_b, memv_b, biasC);

  gemm_kernel<true><<<dim3(35, 32), 256, 0, stream>>>(xb, WT, Cbuf, biasC, 4096, 4480, 1024);

  repack_kernel<<<1024, 256, 0, stream>>>(Cbuf, Kc, Vt);
  attn_kernel<<<dim3(96, 32), 128, 0, stream>>>(Cbuf, Kc, Vt, po, pll);
  lines_kernel<<<256, 256, 0, stream>>>(Cbuf, Jw, Jr, rd);
  scanA_kernel<<<1024, 64, 0, stream>>>(Jw, Jr, decay_l, chA);
  scanA2_kernel<<<9, 256, 0, stream>>>(chA, decay_l, Bst);
  scanB_kernel<<<1024, 128, 0, stream>>>(Jw, Jr, rd, Bst, decay_l, sw, sr);
  combine_kernel<<<4096, 256, 0, stream>>>(po, pll, Cbuf, sw, sr, mem_scale, rw_mix, fused);

  gemm_kernel<false><<<dim3(8, 32), 256, 0, stream>>>(fused, outT, d_out, out_b, 4096, 1024, 1024);
}